// Round 1
// baseline (1096.134 us; speedup 1.0000x reference)
//
#include <hip/hip_runtime.h>
#include <hip/hip_bf16.h>

#define NN 50000
#define NE 800000

// ---------------- CSR build ----------------
__global__ __launch_bounds__(256) void k_count(const int* __restrict__ dst, int* __restrict__ cnt) {
    int e = blockIdx.x * 256 + threadIdx.x;
    if (e < NE) atomicAdd(&cnt[dst[e]], 1);
}

__global__ __launch_bounds__(1024) void k_scan(const int* __restrict__ cnt, int* __restrict__ row_start) {
    __shared__ int wsum[16];
    __shared__ int carry;
    int t = threadIdx.x, lane = t & 63, wid = t >> 6;
    if (t == 0) carry = 0;
    __syncthreads();
    for (int base = 0; base < NN; base += 1024) {
        int i = base + t;
        int v = (i < NN) ? cnt[i] : 0;
        int x = v;
        #pragma unroll
        for (int off = 1; off < 64; off <<= 1) {
            int y = __shfl_up(x, off, 64);
            if (lane >= off) x += y;
        }
        if (lane == 63) wsum[wid] = x;
        __syncthreads();
        if (t < 16) {
            int s = wsum[t];
            #pragma unroll
            for (int off = 1; off < 16; off <<= 1) {
                int y = __shfl_up(s, off, 16);
                if (t >= off) s += y;
            }
            wsum[t] = s;
        }
        __syncthreads();
        int pre = (wid ? wsum[wid - 1] : 0) + carry;
        if (i < NN) row_start[i] = pre + x - v;  // exclusive scan
        int total = wsum[15];
        __syncthreads();
        if (t == 0) carry += total;
        __syncthreads();
    }
    if (t == 0) row_start[NN] = carry;
}

__global__ __launch_bounds__(256) void k_scatter(const int* __restrict__ src, const int* __restrict__ dst,
                                                 const int* __restrict__ row_start, int* __restrict__ cursor,
                                                 int* __restrict__ col) {
    int e = blockIdx.x * 256 + threadIdx.x;
    if (e >= NE) return;
    int d = dst[e];
    int p = atomicAdd(&cursor[d], 1);
    col[row_start[d] + p] = src[e];
}

// ---------------- mean aggregation: one wave per dst node ----------------
template <int C>
__global__ __launch_bounds__(256) void k_agg(const float* __restrict__ h,
                                             const int* __restrict__ row_start,
                                             const int* __restrict__ col,
                                             float* __restrict__ mean) {
    int lane = threadIdx.x & 63;
    int n = blockIdx.x * 4 + (threadIdx.x >> 6);
    if (n >= NN) return;
    int beg = row_start[n], end = row_start[n + 1];
    int d = end - beg;
    float inv = 1.0f / (float)(d > 1 ? d : 1);
    if constexpr (C == 256) {
        float4 a = make_float4(0.f, 0.f, 0.f, 0.f);
        for (int e = beg; e < end; ++e) {
            int s = col[e];
            float4 v = *reinterpret_cast<const float4*>(h + (size_t)s * 256 + lane * 4);
            a.x += v.x; a.y += v.y; a.z += v.z; a.w += v.w;
        }
        a.x *= inv; a.y *= inv; a.z *= inv; a.w *= inv;
        *reinterpret_cast<float4*>(mean + (size_t)n * 256 + lane * 4) = a;
    } else {
        float2 a = make_float2(0.f, 0.f);
        for (int e = beg; e < end; ++e) {
            int s = col[e];
            float2 v = *reinterpret_cast<const float2*>(h + (size_t)s * 128 + lane * 2);
            a.x += v.x; a.y += v.y;
        }
        a.x *= inv; a.y *= inv;
        *reinterpret_cast<float2*>(mean + (size_t)n * 128 + lane * 2) = a;
    }
}

// ---------------- fused dual GEMM: z = mean@Wl^T + h@Wr^T + bl ----------------
// Block: 256 threads, tile 64 rows x 64 cols, 4x4 micro-tile per thread.
template <int C>
__global__ __launch_bounds__(256) void k_gemm(const float* __restrict__ Am, const float* __restrict__ Ah,
                                              const float* __restrict__ Wl, const float* __restrict__ Wr,
                                              const float* __restrict__ bias, float* __restrict__ z) {
    __shared__ float sA[16][72];
    __shared__ float sB[16][72];
    int t = threadIdx.x;
    int row0 = blockIdx.x * 64, col0 = blockIdx.y * 64;
    int lr = t >> 2, lk = (t & 3) * 4;
    int tx = t & 15, ty = t >> 4;
    float acc[4][4] = {{0.f}};
    #pragma unroll
    for (int seg = 0; seg < 2; ++seg) {
        const float* __restrict__ A = seg ? Ah : Am;
        const float* __restrict__ W = seg ? Wr : Wl;
        for (int kk = 0; kk < C; kk += 16) {
            int ar = row0 + lr;
            float4 av = (ar < NN) ? *reinterpret_cast<const float4*>(A + (size_t)ar * C + kk + lk)
                                  : make_float4(0.f, 0.f, 0.f, 0.f);
            float4 bv = *reinterpret_cast<const float4*>(W + (size_t)(col0 + lr) * C + kk + lk);
            __syncthreads();
            sA[lk + 0][lr] = av.x; sA[lk + 1][lr] = av.y; sA[lk + 2][lr] = av.z; sA[lk + 3][lr] = av.w;
            sB[lk + 0][lr] = bv.x; sB[lk + 1][lr] = bv.y; sB[lk + 2][lr] = bv.z; sB[lk + 3][lr] = bv.w;
            __syncthreads();
            #pragma unroll
            for (int k = 0; k < 16; ++k) {
                float4 a = *reinterpret_cast<const float4*>(&sA[k][ty * 4]);
                float4 b = *reinterpret_cast<const float4*>(&sB[k][tx * 4]);
                acc[0][0] += a.x * b.x; acc[0][1] += a.x * b.y; acc[0][2] += a.x * b.z; acc[0][3] += a.x * b.w;
                acc[1][0] += a.y * b.x; acc[1][1] += a.y * b.y; acc[1][2] += a.y * b.z; acc[1][3] += a.y * b.w;
                acc[2][0] += a.z * b.x; acc[2][1] += a.z * b.y; acc[2][2] += a.z * b.z; acc[2][3] += a.z * b.w;
                acc[3][0] += a.w * b.x; acc[3][1] += a.w * b.y; acc[3][2] += a.w * b.z; acc[3][3] += a.w * b.w;
            }
        }
    }
    float4 bb = *reinterpret_cast<const float4*>(&bias[col0 + tx * 4]);
    #pragma unroll
    for (int i = 0; i < 4; ++i) {
        int r = row0 + ty * 4 + i;
        if (r < NN) {
            float4 o;
            o.x = acc[i][0] + bb.x;
            o.y = acc[i][1] + bb.y;
            o.z = acc[i][2] + bb.z;
            o.w = acc[i][3] + bb.w;
            *reinterpret_cast<float4*>(z + (size_t)r * 256 + col0 + tx * 4) = o;
        }
    }
}

// ---------------- BatchNorm ----------------
__global__ __launch_bounds__(256) void k_bnstats(const float* __restrict__ z, float* __restrict__ st) {
    int c = threadIdx.x;
    float s = 0.f, ss = 0.f;
    for (int n = blockIdx.x; n < NN; n += gridDim.x) {
        float v = z[(size_t)n * 256 + c];
        s += v; ss += v * v;
    }
    atomicAdd(&st[c], s);
    atomicAdd(&st[256 + c], ss);
}

__global__ __launch_bounds__(256) void k_bnfin(const float* __restrict__ st, const float* __restrict__ g,
                                               const float* __restrict__ b, float* __restrict__ ss) {
    int c = threadIdx.x;
    float mu = st[c] * (1.0f / NN);
    float var = st[256 + c] * (1.0f / NN) - mu * mu;
    float rstd = rsqrtf(fmaxf(var, 0.f) + 1e-5f);
    float sc = g[c] * rstd;
    ss[c] = sc;
    ss[256 + c] = b[c] - mu * sc;
}

template <bool RELU>
__global__ __launch_bounds__(256) void k_bnapply(const float* __restrict__ zin,
                                                 const float* __restrict__ ss,
                                                 float* __restrict__ hout) {
    int i = blockIdx.x * 256 + threadIdx.x;  // over NN*64 float4 units
    if (i >= NN * 64) return;
    int c4 = (i & 63) * 4;
    float4 v = reinterpret_cast<const float4*>(zin)[i];
    float4 sc = *reinterpret_cast<const float4*>(&ss[c4]);
    float4 sh = *reinterpret_cast<const float4*>(&ss[256 + c4]);
    float4 o;
    o.x = v.x * sc.x + sh.x;
    o.y = v.y * sc.y + sh.y;
    o.z = v.z * sc.z + sh.z;
    o.w = v.w * sc.w + sh.w;
    if (RELU) {
        o.x = fmaxf(o.x, 0.f); o.y = fmaxf(o.y, 0.f);
        o.z = fmaxf(o.z, 0.f); o.w = fmaxf(o.w, 0.f);
    }
    reinterpret_cast<float4*>(hout)[i] = o;
}

extern "C" void kernel_launch(void* const* d_in, const int* in_sizes, int n_in,
                              void* d_out, int out_size, void* d_ws, size_t ws_size,
                              hipStream_t stream) {
    const float* x   = (const float*)d_in[0];
    const int*   ei  = (const int*)d_in[1];
    const float* Wl0 = (const float*)d_in[2];
    const float* bl0 = (const float*)d_in[3];
    const float* Wr0 = (const float*)d_in[4];
    const float* g0  = (const float*)d_in[5];
    const float* b0  = (const float*)d_in[6];
    const float* Wl1 = (const float*)d_in[7];
    const float* bl1 = (const float*)d_in[8];
    const float* Wr1 = (const float*)d_in[9];
    const float* g1  = (const float*)d_in[10];
    const float* b1  = (const float*)d_in[11];
    const float* Wl2 = (const float*)d_in[12];
    const float* bl2 = (const float*)d_in[13];
    const float* Wr2 = (const float*)d_in[14];
    const float* g2  = (const float*)d_in[15];
    const float* b2  = (const float*)d_in[16];
    float* out = (float*)d_out;

    char* ws = (char*)d_ws;
    size_t off = 0;
    auto alloc = [&](size_t bytes) -> void* {
        void* p = ws + off;
        off = (off + bytes + 255) & ~(size_t)255;
        return p;
    };
    float* B0        = (float*)alloc((size_t)NN * 256 * 4);  // mean buffer
    float* B1        = (float*)alloc((size_t)NN * 256 * 4);  // z / h buffer
    int*   cnt       = (int*)alloc((size_t)NN * 4);
    int*   cursor    = (int*)alloc((size_t)NN * 4);
    int*   row_start = (int*)alloc((size_t)(NN + 1) * 4);
    int*   col       = (int*)alloc((size_t)NE * 4);
    float* stats     = (float*)alloc(3 * 512 * 4);
    float* ss0       = (float*)alloc(512 * 4);
    float* ss1       = (float*)alloc(512 * 4);
    float* ss2       = (float*)alloc(512 * 4);

    hipMemsetAsync(cnt, 0, (size_t)NN * 4, stream);
    hipMemsetAsync(cursor, 0, (size_t)NN * 4, stream);
    hipMemsetAsync(stats, 0, 3 * 512 * 4, stream);

    k_count<<<(NE + 255) / 256, 256, 0, stream>>>(ei + NE, cnt);
    k_scan<<<1, 1024, 0, stream>>>(cnt, row_start);
    k_scatter<<<(NE + 255) / 256, 256, 0, stream>>>(ei, ei + NE, row_start, cursor, col);

    dim3 ggrid((NN + 63) / 64, 4);

    // ---- Layer 0 (C=128) ----
    k_agg<128><<<(NN + 3) / 4, 256, 0, stream>>>(x, row_start, col, B0);
    k_gemm<128><<<ggrid, 256, 0, stream>>>(B0, x, Wl0, Wr0, bl0, B1);
    k_bnstats<<<512, 256, 0, stream>>>(B1, stats);
    k_bnfin<<<1, 256, 0, stream>>>(stats, g0, b0, ss0);
    k_bnapply<true><<<12500, 256, 0, stream>>>(B1, ss0, B1);  // h1 = B1

    // ---- Layer 1 (C=256) ----
    k_agg<256><<<(NN + 3) / 4, 256, 0, stream>>>(B1, row_start, col, B0);
    k_gemm<256><<<ggrid, 256, 0, stream>>>(B0, B1, Wl1, Wr1, bl1, out);
    k_bnstats<<<512, 256, 0, stream>>>(out, stats + 512);
    k_bnfin<<<1, 256, 0, stream>>>(stats + 512, g1, b1, ss1);
    k_bnapply<true><<<12500, 256, 0, stream>>>(out, ss1, out);  // h2 = out (scratch use)

    // ---- Layer 2 (C=256) ----
    k_agg<256><<<(NN + 3) / 4, 256, 0, stream>>>(out, row_start, col, B0);
    k_gemm<256><<<ggrid, 256, 0, stream>>>(B0, out, Wl2, Wr2, bl2, B1);
    k_bnstats<<<512, 256, 0, stream>>>(B1, stats + 1024);
    k_bnfin<<<1, 256, 0, stream>>>(stats + 1024, g2, b2, ss2);
    k_bnapply<false><<<12500, 256, 0, stream>>>(B1, ss2, out);
}

// Round 2
// 742.478 us; speedup vs baseline: 1.4763x; 1.4763x over previous
//
#include <hip/hip_runtime.h>
#include <hip/hip_bf16.h>

#define NN 50000
#define NE 800000

typedef __attribute__((ext_vector_type(8))) short short8;
typedef __attribute__((ext_vector_type(4))) float f32x4;

__device__ inline float bf2f(unsigned short u) {
    unsigned v = (unsigned)u << 16;
    return __builtin_bit_cast(float, v);
}
__device__ inline unsigned short f2bf(float f) {
    return __builtin_bit_cast(unsigned short, __float2bfloat16(f));
}

// ---------------- CSR build ----------------
__global__ __launch_bounds__(256) void k_count(const int* __restrict__ dst, int* __restrict__ cnt) {
    int e = blockIdx.x * 256 + threadIdx.x;
    if (e < NE) atomicAdd(&cnt[dst[e]], 1);
}

__global__ __launch_bounds__(1024) void k_scan(const int* __restrict__ cnt, int* __restrict__ row_start) {
    __shared__ int wsum[16];
    __shared__ int carry;
    int t = threadIdx.x, lane = t & 63, wid = t >> 6;
    if (t == 0) carry = 0;
    __syncthreads();
    for (int base = 0; base < NN; base += 1024) {
        int i = base + t;
        int v = (i < NN) ? cnt[i] : 0;
        int x = v;
        #pragma unroll
        for (int off = 1; off < 64; off <<= 1) {
            int y = __shfl_up(x, off, 64);
            if (lane >= off) x += y;
        }
        if (lane == 63) wsum[wid] = x;
        __syncthreads();
        if (t < 16) {
            int s = wsum[t];
            #pragma unroll
            for (int off = 1; off < 16; off <<= 1) {
                int y = __shfl_up(s, off, 16);
                if (t >= off) s += y;
            }
            wsum[t] = s;
        }
        __syncthreads();
        int pre = (wid ? wsum[wid - 1] : 0) + carry;
        if (i < NN) row_start[i] = pre + x - v;  // exclusive scan
        int total = wsum[15];
        __syncthreads();
        if (t == 0) carry += total;
        __syncthreads();
    }
    if (t == 0) row_start[NN] = carry;
}

__global__ __launch_bounds__(256) void k_scatter(const int* __restrict__ src, const int* __restrict__ dst,
                                                 const int* __restrict__ row_start, int* __restrict__ cursor,
                                                 int* __restrict__ col) {
    int e = blockIdx.x * 256 + threadIdx.x;
    if (e >= NE) return;
    int d = dst[e];
    int p = atomicAdd(&cursor[d], 1);
    col[row_start[d] + p] = src[e];
}

// ---------------- conversions ----------------
__global__ __launch_bounds__(256) void k_f2b(const float* __restrict__ in, unsigned short* __restrict__ out, int n4) {
    int i = blockIdx.x * 256 + threadIdx.x;  // over n4 float4 units
    if (i >= n4) return;
    float4 v = reinterpret_cast<const float4*>(in)[i];
    ushort4 o;
    o.x = f2bf(v.x); o.y = f2bf(v.y); o.z = f2bf(v.z); o.w = f2bf(v.w);
    reinterpret_cast<ushort4*>(out)[i] = o;
}

// pack [Wl | Wr] -> bf16 W[256][2C]
__global__ __launch_bounds__(256) void k_packw(const float* __restrict__ Wl, const float* __restrict__ Wr,
                                               unsigned short* __restrict__ Wb, int C) {
    int K = 2 * C;
    int idx = blockIdx.x * 256 + threadIdx.x;
    if (idx >= 256 * K) return;
    int n = idx / K, k = idx % K;
    float v = (k < C) ? Wl[n * C + k] : Wr[n * C + (k - C)];
    Wb[idx] = f2bf(v);
}

// ---------------- mean aggregation (bf16 in/out): one wave per dst node ----------------
template <int C>
__global__ __launch_bounds__(256) void k_aggb(const unsigned short* __restrict__ h,
                                              const int* __restrict__ row_start,
                                              const int* __restrict__ col,
                                              unsigned short* __restrict__ mean) {
    int lane = threadIdx.x & 63;
    int n = blockIdx.x * 4 + (threadIdx.x >> 6);
    if (n >= NN) return;
    int beg = row_start[n], end = row_start[n + 1];
    int d = end - beg;
    float inv = 1.0f / (float)(d > 1 ? d : 1);
    if constexpr (C == 256) {
        float a0 = 0.f, a1 = 0.f, a2 = 0.f, a3 = 0.f;
        for (int e = beg; e < end; ++e) {
            int s = col[e];
            ushort4 v = *reinterpret_cast<const ushort4*>(h + (size_t)s * 256 + lane * 4);
            a0 += bf2f(v.x); a1 += bf2f(v.y); a2 += bf2f(v.z); a3 += bf2f(v.w);
        }
        ushort4 o;
        o.x = f2bf(a0 * inv); o.y = f2bf(a1 * inv); o.z = f2bf(a2 * inv); o.w = f2bf(a3 * inv);
        *reinterpret_cast<ushort4*>(mean + (size_t)n * 256 + lane * 4) = o;
    } else {
        float a0 = 0.f, a1 = 0.f;
        for (int e = beg; e < end; ++e) {
            int s = col[e];
            ushort2 v = *reinterpret_cast<const ushort2*>(h + (size_t)s * 128 + lane * 2);
            a0 += bf2f(v.x); a1 += bf2f(v.y);
        }
        ushort2 o;
        o.x = f2bf(a0 * inv); o.y = f2bf(a1 * inv);
        *reinterpret_cast<ushort2*>(mean + (size_t)n * 128 + lane * 2) = o;
    }
}

// ---------------- MFMA dual GEMM: z = [mean|h] @ W^T + bias ----------------
// Block = 256 threads (4 waves). Tile: 64 rows x 256 cols (wave w owns cols w*64..w*64+63).
// A read exactly once from global; W (<=256KB bf16) stays L2-resident.
template <int C>
__global__ __launch_bounds__(256) void k_gemm_mfma(const unsigned short* __restrict__ Am,
                                                   const unsigned short* __restrict__ Ah,
                                                   const unsigned short* __restrict__ Wb,  // 256 x 2C
                                                   const float* __restrict__ bias,
                                                   float* __restrict__ z) {
    constexpr int K = 2 * C;
    int lane = threadIdx.x & 63;
    int wid  = threadIdx.x >> 6;
    int row0 = blockIdx.x * 64;
    int col0 = wid * 64;
    int rl = lane & 15;   // row (A) / col (B) within fragment
    int kh = lane >> 4;   // k-subchunk of 8

    f32x4 acc[4][4] = {};

    int arow[4];
    #pragma unroll
    for (int m = 0; m < 4; ++m) {
        int r = row0 + m * 16 + rl;
        arow[m] = (r < NN) ? r : 0;  // clamped rows are computed but never stored
    }

    #pragma unroll
    for (int seg = 0; seg < 2; ++seg) {
        const unsigned short* __restrict__ A = seg ? Ah : Am;
        for (int kk = 0; kk < C; kk += 32) {
            short8 a[4], b[4];
            #pragma unroll
            for (int m = 0; m < 4; ++m)
                a[m] = *reinterpret_cast<const short8*>(A + (size_t)arow[m] * C + kk + kh * 8);
            #pragma unroll
            for (int n = 0; n < 4; ++n)
                b[n] = *reinterpret_cast<const short8*>(Wb + (size_t)(col0 + n * 16 + rl) * K + seg * C + kk + kh * 8);
            #pragma unroll
            for (int m = 0; m < 4; ++m)
                #pragma unroll
                for (int n = 0; n < 4; ++n)
                    acc[m][n] = __builtin_amdgcn_mfma_f32_16x16x32_bf16(a[m], b[n], acc[m][n], 0, 0, 0);
        }
    }

    // epilogue: D layout col=lane&15, row=(lane>>4)*4+j  [m89]
    int cbase = lane & 15;
    int rbase = (lane >> 4) * 4;
    #pragma unroll
    for (int m = 0; m < 4; ++m) {
        #pragma unroll
        for (int j = 0; j < 4; ++j) {
            int r = row0 + m * 16 + rbase + j;
            if (r < NN) {
                #pragma unroll
                for (int n = 0; n < 4; ++n) {
                    int c = col0 + n * 16 + cbase;
                    z[(size_t)r * 256 + c] = acc[m][n][j] + bias[c];
                }
            }
        }
    }
}

// ---------------- BatchNorm ----------------
__global__ __launch_bounds__(256) void k_bnstats(const float* __restrict__ z, float* __restrict__ st) {
    int c = threadIdx.x;
    float s = 0.f, ss = 0.f;
    for (int n = blockIdx.x; n < NN; n += gridDim.x) {
        float v = z[(size_t)n * 256 + c];
        s += v; ss += v * v;
    }
    atomicAdd(&st[c], s);
    atomicAdd(&st[256 + c], ss);
}

__global__ __launch_bounds__(256) void k_bnfin(const float* __restrict__ st, const float* __restrict__ g,
                                               const float* __restrict__ b, float* __restrict__ ss) {
    int c = threadIdx.x;
    float mu = st[c] * (1.0f / NN);
    float var = st[256 + c] * (1.0f / NN) - mu * mu;
    float rstd = rsqrtf(fmaxf(var, 0.f) + 1e-5f);
    float sc = g[c] * rstd;
    ss[c] = sc;
    ss[256 + c] = b[c] - mu * sc;
}

// BN apply, bf16 output (+ReLU) for hidden layers
__global__ __launch_bounds__(256) void k_bnapply_b(const float* __restrict__ zin,
                                                   const float* __restrict__ ss,
                                                   unsigned short* __restrict__ hout) {
    int i = blockIdx.x * 256 + threadIdx.x;  // over NN*64 groups of 4 channels
    if (i >= NN * 64) return;
    int c4 = (i & 63) * 4;
    float4 v = reinterpret_cast<const float4*>(zin)[i];
    float4 sc = *reinterpret_cast<const float4*>(&ss[c4]);
    float4 sh = *reinterpret_cast<const float4*>(&ss[256 + c4]);
    ushort4 o;
    o.x = f2bf(fmaxf(v.x * sc.x + sh.x, 0.f));
    o.y = f2bf(fmaxf(v.y * sc.y + sh.y, 0.f));
    o.z = f2bf(fmaxf(v.z * sc.z + sh.z, 0.f));
    o.w = f2bf(fmaxf(v.w * sc.w + sh.w, 0.f));
    reinterpret_cast<ushort4*>(hout)[i] = o;
}

// BN apply, fp32 output, no ReLU (final layer)
__global__ __launch_bounds__(256) void k_bnapply_f(const float* __restrict__ zin,
                                                   const float* __restrict__ ss,
                                                   float* __restrict__ hout) {
    int i = blockIdx.x * 256 + threadIdx.x;
    if (i >= NN * 64) return;
    int c4 = (i & 63) * 4;
    float4 v = reinterpret_cast<const float4*>(zin)[i];
    float4 sc = *reinterpret_cast<const float4*>(&ss[c4]);
    float4 sh = *reinterpret_cast<const float4*>(&ss[256 + c4]);
    float4 o;
    o.x = v.x * sc.x + sh.x;
    o.y = v.y * sc.y + sh.y;
    o.z = v.z * sc.z + sh.z;
    o.w = v.w * sc.w + sh.w;
    reinterpret_cast<float4*>(hout)[i] = o;
}

extern "C" void kernel_launch(void* const* d_in, const int* in_sizes, int n_in,
                              void* d_out, int out_size, void* d_ws, size_t ws_size,
                              hipStream_t stream) {
    const float* x   = (const float*)d_in[0];
    const int*   ei  = (const int*)d_in[1];
    const float* Wl0 = (const float*)d_in[2];
    const float* bl0 = (const float*)d_in[3];
    const float* Wr0 = (const float*)d_in[4];
    const float* g0  = (const float*)d_in[5];
    const float* b0  = (const float*)d_in[6];
    const float* Wl1 = (const float*)d_in[7];
    const float* bl1 = (const float*)d_in[8];
    const float* Wr1 = (const float*)d_in[9];
    const float* g1  = (const float*)d_in[10];
    const float* b1  = (const float*)d_in[11];
    const float* Wl2 = (const float*)d_in[12];
    const float* bl2 = (const float*)d_in[13];
    const float* Wr2 = (const float*)d_in[14];
    const float* g2  = (const float*)d_in[15];
    const float* b2  = (const float*)d_in[16];
    float* out = (float*)d_out;

    char* ws = (char*)d_ws;
    size_t off = 0;
    auto alloc = [&](size_t bytes) -> void* {
        void* p = ws + off;
        off = (off + bytes + 255) & ~(size_t)255;
        return p;
    };
    float*          Z         = (float*)alloc((size_t)NN * 256 * 4);          // GEMM output fp32
    unsigned short* Hb        = (unsigned short*)alloc((size_t)NN * 256 * 2); // features bf16
    unsigned short* Mb        = (unsigned short*)alloc((size_t)NN * 256 * 2); // mean bf16
    int*   cnt       = (int*)alloc((size_t)NN * 4);
    int*   cursor    = (int*)alloc((size_t)NN * 4);
    int*   row_start = (int*)alloc((size_t)(NN + 1) * 4);
    int*   col       = (int*)alloc((size_t)NE * 4);
    float* stats     = (float*)alloc(3 * 512 * 4);
    float* ss0       = (float*)alloc(512 * 4);
    float* ss1       = (float*)alloc(512 * 4);
    float* ss2       = (float*)alloc(512 * 4);
    unsigned short* Wb0 = (unsigned short*)alloc((size_t)256 * 256 * 2);
    unsigned short* Wb1 = (unsigned short*)alloc((size_t)256 * 512 * 2);
    unsigned short* Wb2 = (unsigned short*)alloc((size_t)256 * 512 * 2);

    hipMemsetAsync(cnt, 0, (size_t)NN * 4, stream);
    hipMemsetAsync(cursor, 0, (size_t)NN * 4, stream);
    hipMemsetAsync(stats, 0, 3 * 512 * 4, stream);

    // CSR + conversions
    k_count<<<(NE + 255) / 256, 256, 0, stream>>>(ei + NE, cnt);
    k_scan<<<1, 1024, 0, stream>>>(cnt, row_start);
    k_scatter<<<(NE + 255) / 256, 256, 0, stream>>>(ei, ei + NE, row_start, cursor, col);
    k_f2b<<<(NN * 32 + 255) / 256, 256, 0, stream>>>(x, Hb, NN * 32);  // x -> bf16 (NN*128 elems = NN*32 float4)
    k_packw<<<(256 * 256 + 255) / 256, 256, 0, stream>>>(Wl0, Wr0, Wb0, 128);
    k_packw<<<(256 * 512 + 255) / 256, 256, 0, stream>>>(Wl1, Wr1, Wb1, 256);
    k_packw<<<(256 * 512 + 255) / 256, 256, 0, stream>>>(Wl2, Wr2, Wb2, 256);

    int ggrid = (NN + 63) / 64;

    // ---- Layer 0 (C=128) ----
    k_aggb<128><<<(NN + 3) / 4, 256, 0, stream>>>(Hb, row_start, col, Mb);
    k_gemm_mfma<128><<<ggrid, 256, 0, stream>>>(Mb, Hb, Wb0, bl0, Z);
    k_bnstats<<<512, 256, 0, stream>>>(Z, stats);
    k_bnfin<<<1, 256, 0, stream>>>(stats, g0, b0, ss0);
    k_bnapply_b<<<12500, 256, 0, stream>>>(Z, ss0, Hb);

    // ---- Layer 1 (C=256) ----
    k_aggb<256><<<(NN + 3) / 4, 256, 0, stream>>>(Hb, row_start, col, Mb);
    k_gemm_mfma<256><<<ggrid, 256, 0, stream>>>(Mb, Hb, Wb1, bl1, Z);
    k_bnstats<<<512, 256, 0, stream>>>(Z, stats + 512);
    k_bnfin<<<1, 256, 0, stream>>>(stats + 512, g1, b1, ss1);
    k_bnapply_b<<<12500, 256, 0, stream>>>(Z, ss1, Hb);

    // ---- Layer 2 (C=256) ----
    k_aggb<256><<<(NN + 3) / 4, 256, 0, stream>>>(Hb, row_start, col, Mb);
    k_gemm_mfma<256><<<ggrid, 256, 0, stream>>>(Mb, Hb, Wb2, bl2, Z);
    k_bnstats<<<512, 256, 0, stream>>>(Z, stats + 1024);
    k_bnfin<<<1, 256, 0, stream>>>(stats + 1024, g2, b2, ss2);
    k_bnapply_f<<<12500, 256, 0, stream>>>(Z, ss2, out);
}

// Round 3
// 516.895 us; speedup vs baseline: 2.1206x; 1.4364x over previous
//
#include <hip/hip_runtime.h>
#include <hip/hip_bf16.h>

#define NN 50000
#define NE 800000
#define NB ((NN + 1023) / 1024)

typedef __attribute__((ext_vector_type(8))) short short8;
typedef __attribute__((ext_vector_type(4))) float f32x4;

__device__ inline float bf2f(unsigned short u) {
    unsigned v = (unsigned)u << 16;
    return __builtin_bit_cast(float, v);
}
__device__ inline unsigned short f2bf(float f) {
    return __builtin_bit_cast(unsigned short, __float2bfloat16(f));
}

// ---------------- CSR build ----------------
__global__ __launch_bounds__(256) void k_count(const int* __restrict__ dst, int* __restrict__ cnt) {
    int e = blockIdx.x * 256 + threadIdx.x;
    if (e < NE) atomicAdd(&cnt[dst[e]], 1);
}

// 3-phase scan: A = per-block (1024) exclusive scan + block total
__global__ __launch_bounds__(1024) void k_scanA(const int* __restrict__ cnt, int* __restrict__ row_start,
                                                int* __restrict__ bsum) {
    __shared__ int wsum[16];
    int t = threadIdx.x, lane = t & 63, wid = t >> 6;
    int i = blockIdx.x * 1024 + t;
    int v = (i < NN) ? cnt[i] : 0;
    int x = v;
    #pragma unroll
    for (int off = 1; off < 64; off <<= 1) {
        int y = __shfl_up(x, off, 64);
        if (lane >= off) x += y;
    }
    if (lane == 63) wsum[wid] = x;
    __syncthreads();
    if (t < 16) {
        int s = wsum[t];
        #pragma unroll
        for (int off = 1; off < 16; off <<= 1) {
            int y = __shfl_up(s, off, 16);
            if (t >= off) s += y;
        }
        wsum[t] = s;
    }
    __syncthreads();
    int pre = wid ? wsum[wid - 1] : 0;
    if (i < NN) row_start[i] = pre + x - v;  // block-local exclusive
    if (t == 0) bsum[blockIdx.x] = wsum[15];
}

// B = scan of 49 block totals (single wave)
__global__ __launch_bounds__(64) void k_scanB(const int* __restrict__ bsum, int* __restrict__ boff,
                                              int* __restrict__ row_start) {
    int l = threadIdx.x;
    int v = (l < NB) ? bsum[l] : 0;
    int x = v;
    #pragma unroll
    for (int off = 1; off < 64; off <<= 1) {
        int y = __shfl_up(x, off, 64);
        if (l >= off) x += y;
    }
    boff[l] = x - v;
    if (l == 63) row_start[NN] = x;  // total
}

// C = add block offsets; also init scatter cursor
__global__ __launch_bounds__(1024) void k_scanC(int* __restrict__ row_start, const int* __restrict__ boff,
                                                int* __restrict__ cursor) {
    int i = blockIdx.x * 1024 + threadIdx.x;
    if (i < NN) {
        int rs = row_start[i] + boff[blockIdx.x];
        row_start[i] = rs;
        cursor[i] = rs;
    }
}

__global__ __launch_bounds__(256) void k_scatter(const int* __restrict__ src, const int* __restrict__ dst,
                                                 int* __restrict__ cursor, int* __restrict__ col) {
    int e = blockIdx.x * 256 + threadIdx.x;
    if (e >= NE) return;
    int d = dst[e];
    int p = atomicAdd(&cursor[d], 1);
    col[p] = src[e];
}

// ---------------- conversions ----------------
__global__ __launch_bounds__(256) void k_f2b(const float* __restrict__ in, unsigned short* __restrict__ out, int n4) {
    int i = blockIdx.x * 256 + threadIdx.x;
    if (i >= n4) return;
    float4 v = reinterpret_cast<const float4*>(in)[i];
    ushort4 o;
    o.x = f2bf(v.x); o.y = f2bf(v.y); o.z = f2bf(v.z); o.w = f2bf(v.w);
    reinterpret_cast<ushort4*>(out)[i] = o;
}

// pack [Wl | Wr] -> bf16 W[256][2C]
__global__ __launch_bounds__(256) void k_packw(const float* __restrict__ Wl, const float* __restrict__ Wr,
                                               unsigned short* __restrict__ Wb, int C) {
    int K = 2 * C;
    int idx = blockIdx.x * 256 + threadIdx.x;
    if (idx >= 256 * K) return;
    int n = idx / K, k = idx % K;
    float v = (k < C) ? Wl[n * C + k] : Wr[n * C + (k - C)];
    Wb[idx] = f2bf(v);
}

// ---------------- mean aggregation: C/8 lanes per node, 16B/lane, 4 gathers in flight ----------------
template <int C>
__global__ __launch_bounds__(256) void k_agg2(const unsigned short* __restrict__ h,
                                              const int* __restrict__ row_start,
                                              const int* __restrict__ col,
                                              unsigned short* __restrict__ mean) {
    constexpr int LPN = C / 8;       // lanes per node: 32 (C=256) or 16 (C=128)
    constexpr int NPB = 256 / LPN;   // nodes per block: 8 or 16
    int l = threadIdx.x & (LPN - 1);
    int n = blockIdx.x * NPB + (threadIdx.x / LPN);
    if (n >= NN) return;
    int beg = row_start[n], end = row_start[n + 1];
    float inv = 1.0f / (float)((end - beg) > 1 ? (end - beg) : 1);
    float a[8] = {0.f, 0.f, 0.f, 0.f, 0.f, 0.f, 0.f, 0.f};
    const unsigned short* hp = h + l * 8;
    for (int base = beg; base < end; base += LPN) {
        int idx = base + l;
        int my = (idx < end) ? col[idx] : 0;
        int cnt = end - base; if (cnt > LPN) cnt = LPN;
        int j = 0;
        for (; j + 4 <= cnt; j += 4) {
            int s0 = __shfl(my, j + 0, LPN);
            int s1 = __shfl(my, j + 1, LPN);
            int s2 = __shfl(my, j + 2, LPN);
            int s3 = __shfl(my, j + 3, LPN);
            short8 v0 = *reinterpret_cast<const short8*>(hp + (size_t)s0 * C);
            short8 v1 = *reinterpret_cast<const short8*>(hp + (size_t)s1 * C);
            short8 v2 = *reinterpret_cast<const short8*>(hp + (size_t)s2 * C);
            short8 v3 = *reinterpret_cast<const short8*>(hp + (size_t)s3 * C);
            #pragma unroll
            for (int k = 0; k < 8; ++k) {
                a[k] += bf2f((unsigned short)v0[k]);
                a[k] += bf2f((unsigned short)v1[k]);
                a[k] += bf2f((unsigned short)v2[k]);
                a[k] += bf2f((unsigned short)v3[k]);
            }
        }
        for (; j < cnt; ++j) {
            int s = __shfl(my, j, LPN);
            short8 v = *reinterpret_cast<const short8*>(hp + (size_t)s * C);
            #pragma unroll
            for (int k = 0; k < 8; ++k) a[k] += bf2f((unsigned short)v[k]);
        }
    }
    unsigned short o[8];
    #pragma unroll
    for (int k = 0; k < 8; ++k) o[k] = f2bf(a[k] * inv);
    *reinterpret_cast<short8*>(mean + (size_t)n * C + l * 8) = *reinterpret_cast<short8*>(o);
}

// ---------------- MFMA dual GEMM + fused BN stats: z = [mean|h] @ W^T ----------------
// (bias omitted: BatchNorm immediately after makes per-channel bias a no-op)
template <int C>
__global__ __launch_bounds__(256) void k_gemm_mfma(const unsigned short* __restrict__ Am,
                                                   const unsigned short* __restrict__ Ah,
                                                   const unsigned short* __restrict__ Wb,  // 256 x 2C
                                                   float* __restrict__ z,
                                                   float* __restrict__ st) {
    constexpr int K = 2 * C;
    int lane = threadIdx.x & 63;
    int wid  = threadIdx.x >> 6;
    int row0 = blockIdx.x * 64;
    int col0 = wid * 64;
    int rl = lane & 15;
    int kh = lane >> 4;

    f32x4 acc[4][4] = {};

    int arow[4];
    #pragma unroll
    for (int m = 0; m < 4; ++m) {
        int r = row0 + m * 16 + rl;
        arow[m] = (r < NN) ? r : 0;
    }

    #pragma unroll
    for (int seg = 0; seg < 2; ++seg) {
        const unsigned short* __restrict__ A = seg ? Ah : Am;
        for (int kk = 0; kk < C; kk += 32) {
            short8 a[4], b[4];
            #pragma unroll
            for (int m = 0; m < 4; ++m)
                a[m] = *reinterpret_cast<const short8*>(A + (size_t)arow[m] * C + kk + kh * 8);
            #pragma unroll
            for (int n = 0; n < 4; ++n)
                b[n] = *reinterpret_cast<const short8*>(Wb + (size_t)(col0 + n * 16 + rl) * K + seg * C + kk + kh * 8);
            #pragma unroll
            for (int m = 0; m < 4; ++m)
                #pragma unroll
                for (int n = 0; n < 4; ++n)
                    acc[m][n] = __builtin_amdgcn_mfma_f32_16x16x32_bf16(a[m], b[n], acc[m][n], 0, 0, 0);
        }
    }

    // epilogue: store + per-column partial sums (D layout: col=lane&15, row=(lane>>4)*4+j)
    int cbase = lane & 15;
    int rbase = (lane >> 4) * 4;
    float s1[4] = {0.f, 0.f, 0.f, 0.f};
    float s2[4] = {0.f, 0.f, 0.f, 0.f};
    #pragma unroll
    for (int m = 0; m < 4; ++m) {
        #pragma unroll
        for (int j = 0; j < 4; ++j) {
            int r = row0 + m * 16 + rbase + j;
            if (r < NN) {
                #pragma unroll
                for (int n = 0; n < 4; ++n) {
                    float v = acc[m][n][j];
                    z[(size_t)r * 256 + col0 + n * 16 + cbase] = v;
                    s1[n] += v;
                    s2[n] += v * v;
                }
            }
        }
    }
    #pragma unroll
    for (int n = 0; n < 4; ++n) {
        s1[n] += __shfl_xor(s1[n], 16);
        s1[n] += __shfl_xor(s1[n], 32);
        s2[n] += __shfl_xor(s2[n], 16);
        s2[n] += __shfl_xor(s2[n], 32);
    }
    if (lane < 16) {
        #pragma unroll
        for (int n = 0; n < 4; ++n) {
            int c = col0 + n * 16 + lane;
            atomicAdd(&st[c], s1[n]);
            atomicAdd(&st[256 + c], s2[n]);
        }
    }
}

// ---------------- BatchNorm ----------------
__global__ __launch_bounds__(256) void k_bnfin(const float* __restrict__ st, const float* __restrict__ g,
                                               const float* __restrict__ b, float* __restrict__ ss) {
    int c = threadIdx.x;
    float mu = st[c] * (1.0f / NN);
    float var = st[256 + c] * (1.0f / NN) - mu * mu;
    float rstd = rsqrtf(fmaxf(var, 0.f) + 1e-5f);
    float sc = g[c] * rstd;
    ss[c] = sc;
    ss[256 + c] = b[c] - mu * sc;
}

__global__ __launch_bounds__(256) void k_bnapply_b(const float* __restrict__ zin,
                                                   const float* __restrict__ ss,
                                                   unsigned short* __restrict__ hout) {
    int i = blockIdx.x * 256 + threadIdx.x;
    if (i >= NN * 64) return;
    int c4 = (i & 63) * 4;
    float4 v = reinterpret_cast<const float4*>(zin)[i];
    float4 sc = *reinterpret_cast<const float4*>(&ss[c4]);
    float4 sh = *reinterpret_cast<const float4*>(&ss[256 + c4]);
    ushort4 o;
    o.x = f2bf(fmaxf(v.x * sc.x + sh.x, 0.f));
    o.y = f2bf(fmaxf(v.y * sc.y + sh.y, 0.f));
    o.z = f2bf(fmaxf(v.z * sc.z + sh.z, 0.f));
    o.w = f2bf(fmaxf(v.w * sc.w + sh.w, 0.f));
    reinterpret_cast<ushort4*>(hout)[i] = o;
}

__global__ __launch_bounds__(256) void k_bnapply_f(const float* __restrict__ zin,
                                                   const float* __restrict__ ss,
                                                   float* __restrict__ hout) {
    int i = blockIdx.x * 256 + threadIdx.x;
    if (i >= NN * 64) return;
    int c4 = (i & 63) * 4;
    float4 v = reinterpret_cast<const float4*>(zin)[i];
    float4 sc = *reinterpret_cast<const float4*>(&ss[c4]);
    float4 sh = *reinterpret_cast<const float4*>(&ss[256 + c4]);
    float4 o;
    o.x = v.x * sc.x + sh.x;
    o.y = v.y * sc.y + sh.y;
    o.z = v.z * sc.z + sh.z;
    o.w = v.w * sc.w + sh.w;
    reinterpret_cast<float4*>(hout)[i] = o;
}

extern "C" void kernel_launch(void* const* d_in, const int* in_sizes, int n_in,
                              void* d_out, int out_size, void* d_ws, size_t ws_size,
                              hipStream_t stream) {
    const float* x   = (const float*)d_in[0];
    const int*   ei  = (const int*)d_in[1];
    const float* Wl0 = (const float*)d_in[2];
    const float* Wr0 = (const float*)d_in[4];
    const float* g0  = (const float*)d_in[5];
    const float* b0  = (const float*)d_in[6];
    const float* Wl1 = (const float*)d_in[7];
    const float* Wr1 = (const float*)d_in[9];
    const float* g1  = (const float*)d_in[10];
    const float* b1  = (const float*)d_in[11];
    const float* Wl2 = (const float*)d_in[12];
    const float* Wr2 = (const float*)d_in[14];
    const float* g2  = (const float*)d_in[15];
    const float* b2  = (const float*)d_in[16];
    float* out = (float*)d_out;

    char* ws = (char*)d_ws;
    size_t off = 0;
    auto alloc = [&](size_t bytes) -> void* {
        void* p = ws + off;
        off = (off + bytes + 255) & ~(size_t)255;
        return p;
    };
    float*          Z  = (float*)alloc((size_t)NN * 256 * 4);
    unsigned short* Hb = (unsigned short*)alloc((size_t)NN * 256 * 2);
    unsigned short* Mb = (unsigned short*)alloc((size_t)NN * 256 * 2);
    int*   cnt       = (int*)alloc((size_t)NN * 4);
    int*   cursor    = (int*)alloc((size_t)NN * 4);
    int*   row_start = (int*)alloc((size_t)(NN + 1) * 4);
    int*   col       = (int*)alloc((size_t)NE * 4);
    int*   bsum      = (int*)alloc(64 * 4);
    int*   boff      = (int*)alloc(64 * 4);
    float* stats     = (float*)alloc(3 * 512 * 4);
    float* ss0       = (float*)alloc(512 * 4);
    float* ss1       = (float*)alloc(512 * 4);
    float* ss2       = (float*)alloc(512 * 4);
    unsigned short* Wb0 = (unsigned short*)alloc((size_t)256 * 256 * 2);
    unsigned short* Wb1 = (unsigned short*)alloc((size_t)256 * 512 * 2);
    unsigned short* Wb2 = (unsigned short*)alloc((size_t)256 * 512 * 2);

    hipMemsetAsync(cnt, 0, (size_t)NN * 4, stream);
    hipMemsetAsync(stats, 0, 3 * 512 * 4, stream);

    // CSR + conversions
    k_count<<<(NE + 255) / 256, 256, 0, stream>>>(ei + NE, cnt);
    k_scanA<<<NB, 1024, 0, stream>>>(cnt, row_start, bsum);
    k_scanB<<<1, 64, 0, stream>>>(bsum, boff, row_start);
    k_scanC<<<NB, 1024, 0, stream>>>(row_start, boff, cursor);
    k_scatter<<<(NE + 255) / 256, 256, 0, stream>>>(ei, ei + NE, cursor, col);
    k_f2b<<<(NN * 32 + 255) / 256, 256, 0, stream>>>(x, Hb, NN * 32);
    k_packw<<<(256 * 256 + 255) / 256, 256, 0, stream>>>(Wl0, Wr0, Wb0, 128);
    k_packw<<<(256 * 512 + 255) / 256, 256, 0, stream>>>(Wl1, Wr1, Wb1, 256);
    k_packw<<<(256 * 512 + 255) / 256, 256, 0, stream>>>(Wl2, Wr2, Wb2, 256);

    int ggrid = (NN + 63) / 64;

    // ---- Layer 0 (C=128) ----
    k_agg2<128><<<(NN + 15) / 16, 256, 0, stream>>>(Hb, row_start, col, Mb);
    k_gemm_mfma<128><<<ggrid, 256, 0, stream>>>(Mb, Hb, Wb0, Z, stats);
    k_bnfin<<<1, 256, 0, stream>>>(stats, g0, b0, ss0);
    k_bnapply_b<<<12500, 256, 0, stream>>>(Z, ss0, Hb);

    // ---- Layer 1 (C=256) ----
    k_agg2<256><<<(NN + 7) / 8, 256, 0, stream>>>(Hb, row_start, col, Mb);
    k_gemm_mfma<256><<<ggrid, 256, 0, stream>>>(Mb, Hb, Wb1, Z, stats + 512);
    k_bnfin<<<1, 256, 0, stream>>>(stats + 512, g1, b1, ss1);
    k_bnapply_b<<<12500, 256, 0, stream>>>(Z, ss1, Hb);

    // ---- Layer 2 (C=256) ----
    k_agg2<256><<<(NN + 7) / 8, 256, 0, stream>>>(Hb, row_start, col, Mb);
    k_gemm_mfma<256><<<ggrid, 256, 0, stream>>>(Mb, Hb, Wb2, Z, stats + 1024);
    k_bnfin<<<1, 256, 0, stream>>>(stats + 1024, g2, b2, ss2);
    k_bnapply_f<<<12500, 256, 0, stream>>>(Z, ss2, out);
}

// Round 4
// 410.693 us; speedup vs baseline: 2.6690x; 1.2586x over previous
//
#include <hip/hip_runtime.h>
#include <hip/hip_bf16.h>

#define NN 50000
#define NE 800000
#define NB ((NN + 1023) / 1024)

typedef __attribute__((ext_vector_type(8))) short short8;
typedef __attribute__((ext_vector_type(4))) float f32x4;

#define AS1 __attribute__((address_space(1)))
#define AS3 __attribute__((address_space(3)))

__device__ inline float bf2f(unsigned short u) {
    unsigned v = (unsigned)u << 16;
    return __builtin_bit_cast(float, v);
}
__device__ inline unsigned short f2bf(float f) {
    return __builtin_bit_cast(unsigned short, __float2bfloat16(f));
}

// ---------------- CSR build ----------------
__global__ __launch_bounds__(256) void k_count(const int* __restrict__ dst, int* __restrict__ cnt) {
    int e = blockIdx.x * 256 + threadIdx.x;
    if (e < NE) atomicAdd(&cnt[dst[e]], 1);
}

__global__ __launch_bounds__(1024) void k_scanA(const int* __restrict__ cnt, int* __restrict__ row_start,
                                                int* __restrict__ bsum) {
    __shared__ int wsum[16];
    int t = threadIdx.x, lane = t & 63, wid = t >> 6;
    int i = blockIdx.x * 1024 + t;
    int v = (i < NN) ? cnt[i] : 0;
    int x = v;
    #pragma unroll
    for (int off = 1; off < 64; off <<= 1) {
        int y = __shfl_up(x, off, 64);
        if (lane >= off) x += y;
    }
    if (lane == 63) wsum[wid] = x;
    __syncthreads();
    if (t < 16) {
        int s = wsum[t];
        #pragma unroll
        for (int off = 1; off < 16; off <<= 1) {
            int y = __shfl_up(s, off, 16);
            if (t >= off) s += y;
        }
        wsum[t] = s;
    }
    __syncthreads();
    int pre = wid ? wsum[wid - 1] : 0;
    if (i < NN) row_start[i] = pre + x - v;
    if (t == 0) bsum[blockIdx.x] = wsum[15];
}

__global__ __launch_bounds__(64) void k_scanB(const int* __restrict__ bsum, int* __restrict__ boff,
                                              int* __restrict__ row_start) {
    int l = threadIdx.x;
    int v = (l < NB) ? bsum[l] : 0;
    int x = v;
    #pragma unroll
    for (int off = 1; off < 64; off <<= 1) {
        int y = __shfl_up(x, off, 64);
        if (l >= off) x += y;
    }
    boff[l] = x - v;
    if (l == 63) row_start[NN] = x;
}

__global__ __launch_bounds__(1024) void k_scanC(int* __restrict__ row_start, const int* __restrict__ boff,
                                                int* __restrict__ cursor) {
    int i = blockIdx.x * 1024 + threadIdx.x;
    if (i < NN) {
        int rs = row_start[i] + boff[blockIdx.x];
        row_start[i] = rs;
        cursor[i] = rs;
    }
}

__global__ __launch_bounds__(256) void k_scatter(const int* __restrict__ src, const int* __restrict__ dst,
                                                 int* __restrict__ cursor, int* __restrict__ col) {
    int e = blockIdx.x * 256 + threadIdx.x;
    if (e >= NE) return;
    int d = dst[e];
    int p = atomicAdd(&cursor[d], 1);
    col[p] = src[e];
}

// ---------------- conversions ----------------
// x fp32 [NN][128] -> right half of F0 [NN][256] bf16
__global__ __launch_bounds__(256) void k_f2b_x(const float* __restrict__ in, unsigned short* __restrict__ F0) {
    int i = blockIdx.x * 256 + threadIdx.x;  // NN*32 float4 units
    if (i >= NN * 32) return;
    int row = i >> 5, c4 = (i & 31) * 4;
    float4 v = reinterpret_cast<const float4*>(in)[i];
    ushort4 o;
    o.x = f2bf(v.x); o.y = f2bf(v.y); o.z = f2bf(v.z); o.w = f2bf(v.w);
    *reinterpret_cast<ushort4*>(F0 + (size_t)row * 256 + 128 + c4) = o;
}

// pack [Wl | Wr] -> bf16 W[256][2C]
__global__ __launch_bounds__(256) void k_packw(const float* __restrict__ Wl, const float* __restrict__ Wr,
                                               unsigned short* __restrict__ Wb, int C) {
    int K = 2 * C;
    int idx = blockIdx.x * 256 + threadIdx.x;
    if (idx >= 256 * K) return;
    int n = idx / K, k = idx % K;
    float v = (k < C) ? Wl[n * C + k] : Wr[n * C + (k - C)];
    Wb[idx] = f2bf(v);
}

// ---------------- mean aggregation inside F=[mean|h]: reads F[:,C:], writes F[:,:C] ----------------
template <int C, int S>
__global__ __launch_bounds__(256) void k_agg2(unsigned short* __restrict__ F,
                                              const int* __restrict__ row_start,
                                              const int* __restrict__ col) {
    constexpr int LPN = C / 8;       // lanes per node
    constexpr int NPB = 256 / LPN;   // nodes per block
    int l = threadIdx.x & (LPN - 1);
    int n = blockIdx.x * NPB + (threadIdx.x / LPN);
    if (n >= NN) return;
    int beg = row_start[n], end = row_start[n + 1];
    float inv = 1.0f / (float)((end - beg) > 1 ? (end - beg) : 1);
    float a[8] = {0.f, 0.f, 0.f, 0.f, 0.f, 0.f, 0.f, 0.f};
    const unsigned short* hp = F + C + l * 8;  // h half
    for (int base = beg; base < end; base += LPN) {
        int idx = base + l;
        int my = (idx < end) ? col[idx] : 0;
        int cnt = end - base; if (cnt > LPN) cnt = LPN;
        int j = 0;
        for (; j + 4 <= cnt; j += 4) {
            int s0 = __shfl(my, j + 0, LPN);
            int s1 = __shfl(my, j + 1, LPN);
            int s2 = __shfl(my, j + 2, LPN);
            int s3 = __shfl(my, j + 3, LPN);
            short8 v0 = *reinterpret_cast<const short8*>(hp + (size_t)s0 * S);
            short8 v1 = *reinterpret_cast<const short8*>(hp + (size_t)s1 * S);
            short8 v2 = *reinterpret_cast<const short8*>(hp + (size_t)s2 * S);
            short8 v3 = *reinterpret_cast<const short8*>(hp + (size_t)s3 * S);
            #pragma unroll
            for (int k = 0; k < 8; ++k) {
                a[k] += bf2f((unsigned short)v0[k]);
                a[k] += bf2f((unsigned short)v1[k]);
                a[k] += bf2f((unsigned short)v2[k]);
                a[k] += bf2f((unsigned short)v3[k]);
            }
        }
        for (; j < cnt; ++j) {
            int s = __shfl(my, j, LPN);
            short8 v = *reinterpret_cast<const short8*>(hp + (size_t)s * S);
            #pragma unroll
            for (int k = 0; k < 8; ++k) a[k] += bf2f((unsigned short)v[k]);
        }
    }
    unsigned short o[8];
    #pragma unroll
    for (int k = 0; k < 8; ++k) o[k] = f2bf(a[k] * inv);
    *reinterpret_cast<short8*>(F + (size_t)n * S + l * 8) = *reinterpret_cast<short8*>(o);
}

// ---------------- LDS-staged MFMA GEMM: Z = F @ Wb^T, fused BN stats ----------------
// 512 threads = 8 waves (2 row-groups x 4 col-groups). Tile 128 x 256, BK=32, double-buffered LDS.
// LDS slot swizzle: slot(row,kh) = kh ^ ((row>>1)&3); linear gload_lds dest + pre-swizzled
// global source + swizzled ds_read (rule 21).
template <int K>
__global__ __launch_bounds__(512) void k_gemm2(const unsigned short* __restrict__ F,  // [NN][K]
                                               const unsigned short* __restrict__ Wb, // [256][K]
                                               float* __restrict__ z,
                                               float* __restrict__ st) {
    constexpr int T = K / 32;
    __shared__ __attribute__((aligned(16))) unsigned short sA[2][128 * 32];  // 8 KB each
    __shared__ __attribute__((aligned(16))) unsigned short sB[2][256 * 32];  // 16 KB each
    int tid = threadIdx.x;
    int lane = tid & 63, w = tid >> 6;
    int wr = w >> 2, wc = w & 3;
    int row0 = blockIdx.x * 128;
    int rl = lane & 15, kh = lane >> 4;

    // ---- staging source pointers (per-lane pre-swizzled global addresses) ----
    int s_arow = tid >> 2, s_aslot = tid & 3;
    int s_akh = s_aslot ^ ((s_arow >> 1) & 3);
    int g_arow = row0 + s_arow; if (g_arow >= NN) g_arow = NN - 1;
    const unsigned short* aptr = F + (size_t)g_arow * K + s_akh * 8;

    int u0 = w * 128 + lane;   // B 16B-unit index, call 0
    int u1 = u0 + 64;          // call 1
    int bcol0 = u0 >> 2, bkh0 = (u0 & 3) ^ ((bcol0 >> 1) & 3);
    int bcol1 = u1 >> 2, bkh1 = (u1 & 3) ^ ((bcol1 >> 1) & 3);
    const unsigned short* bptr0 = Wb + (size_t)bcol0 * K + bkh0 * 8;
    const unsigned short* bptr1 = Wb + (size_t)bcol1 * K + bkh1 * 8;

    // ---- ds_read offsets (shorts) ----
    int aoff[4], boff[4];
    #pragma unroll
    for (int m = 0; m < 4; ++m) {
        int r = wr * 64 + m * 16 + rl;
        aoff[m] = r * 32 + (kh ^ ((r >> 1) & 3)) * 8;
    }
    #pragma unroll
    for (int n = 0; n < 4; ++n) {
        int c = wc * 64 + n * 16 + rl;
        boff[n] = c * 32 + (kh ^ ((c >> 1) & 3)) * 8;
    }

    f32x4 acc[4][4] = {};

    auto stage = [&](int buf, int t) {
        int k0 = t * 32;
        __builtin_amdgcn_global_load_lds((const AS1 void*)(aptr + k0),
                                         (AS3 void*)((unsigned short*)sA[buf] + w * 512), 16, 0, 0);
        __builtin_amdgcn_global_load_lds((const AS1 void*)(bptr0 + k0),
                                         (AS3 void*)((unsigned short*)sB[buf] + w * 1024), 16, 0, 0);
        __builtin_amdgcn_global_load_lds((const AS1 void*)(bptr1 + k0),
                                         (AS3 void*)((unsigned short*)sB[buf] + w * 1024 + 512), 16, 0, 0);
    };

    stage(0, 0);
    __syncthreads();
    int cur = 0;
    for (int t = 0; t < T; ++t) {
        if (t + 1 < T) stage(cur ^ 1, t + 1);
        const unsigned short* A_ = sA[cur];
        const unsigned short* B_ = sB[cur];
        short8 af[4], bf_[4];
        #pragma unroll
        for (int m = 0; m < 4; ++m) af[m] = *reinterpret_cast<const short8*>(A_ + aoff[m]);
        #pragma unroll
        for (int n = 0; n < 4; ++n) bf_[n] = *reinterpret_cast<const short8*>(B_ + boff[n]);
        #pragma unroll
        for (int m = 0; m < 4; ++m)
            #pragma unroll
            for (int n = 0; n < 4; ++n)
                acc[m][n] = __builtin_amdgcn_mfma_f32_16x16x32_bf16(af[m], bf_[n], acc[m][n], 0, 0, 0);
        __syncthreads();
        cur ^= 1;
    }

    // ---- epilogue: store Z + per-column BN partial sums ----
    int cbase = lane & 15;
    int rbase = (lane >> 4) * 4;
    float s1[4] = {0.f, 0.f, 0.f, 0.f};
    float s2[4] = {0.f, 0.f, 0.f, 0.f};
    #pragma unroll
    for (int m = 0; m < 4; ++m) {
        #pragma unroll
        for (int j = 0; j < 4; ++j) {
            int r = row0 + wr * 64 + m * 16 + rbase + j;
            if (r < NN) {
                #pragma unroll
                for (int n = 0; n < 4; ++n) {
                    float v = acc[m][n][j];
                    z[(size_t)r * 256 + wc * 64 + n * 16 + cbase] = v;
                    s1[n] += v;
                    s2[n] += v * v;
                }
            }
        }
    }
    #pragma unroll
    for (int n = 0; n < 4; ++n) {
        s1[n] += __shfl_xor(s1[n], 16);
        s1[n] += __shfl_xor(s1[n], 32);
        s2[n] += __shfl_xor(s2[n], 16);
        s2[n] += __shfl_xor(s2[n], 32);
    }
    if (lane < 16) {
        #pragma unroll
        for (int n = 0; n < 4; ++n) {
            int c = wc * 64 + n * 16 + lane;
            atomicAdd(&st[c], s1[n]);
            atomicAdd(&st[256 + c], s2[n]);
        }
    }
}

// ---------------- BatchNorm ----------------
__global__ __launch_bounds__(256) void k_bnfin(const float* __restrict__ st, const float* __restrict__ g,
                                               const float* __restrict__ b, float* __restrict__ ss) {
    int c = threadIdx.x;
    float mu = st[c] * (1.0f / NN);
    float var = st[256 + c] * (1.0f / NN) - mu * mu;
    float rstd = rsqrtf(fmaxf(var, 0.f) + 1e-5f);
    float sc = g[c] * rstd;
    ss[c] = sc;
    ss[256 + c] = b[c] - mu * sc;
}

// BN apply + ReLU -> bf16 into right half of Fnext [NN][512]
__global__ __launch_bounds__(256) void k_bnapply_b(const float* __restrict__ zin,
                                                   const float* __restrict__ ss,
                                                   unsigned short* __restrict__ Fn) {
    int i = blockIdx.x * 256 + threadIdx.x;  // NN*64 float4 units
    if (i >= NN * 64) return;
    int row = i >> 6, c4 = (i & 63) * 4;
    float4 v = reinterpret_cast<const float4*>(zin)[i];
    float4 sc = *reinterpret_cast<const float4*>(&ss[c4]);
    float4 sh = *reinterpret_cast<const float4*>(&ss[256 + c4]);
    ushort4 o;
    o.x = f2bf(fmaxf(v.x * sc.x + sh.x, 0.f));
    o.y = f2bf(fmaxf(v.y * sc.y + sh.y, 0.f));
    o.z = f2bf(fmaxf(v.z * sc.z + sh.z, 0.f));
    o.w = f2bf(fmaxf(v.w * sc.w + sh.w, 0.f));
    *reinterpret_cast<ushort4*>(Fn + (size_t)row * 512 + 256 + c4) = o;
}

// final BN apply, fp32, no ReLU
__global__ __launch_bounds__(256) void k_bnapply_f(const float* __restrict__ zin,
                                                   const float* __restrict__ ss,
                                                   float* __restrict__ hout) {
    int i = blockIdx.x * 256 + threadIdx.x;
    if (i >= NN * 64) return;
    int c4 = (i & 63) * 4;
    float4 v = reinterpret_cast<const float4*>(zin)[i];
    float4 sc = *reinterpret_cast<const float4*>(&ss[c4]);
    float4 sh = *reinterpret_cast<const float4*>(&ss[256 + c4]);
    float4 o;
    o.x = v.x * sc.x + sh.x;
    o.y = v.y * sc.y + sh.y;
    o.z = v.z * sc.z + sh.z;
    o.w = v.w * sc.w + sh.w;
    reinterpret_cast<float4*>(hout)[i] = o;
}

extern "C" void kernel_launch(void* const* d_in, const int* in_sizes, int n_in,
                              void* d_out, int out_size, void* d_ws, size_t ws_size,
                              hipStream_t stream) {
    const float* x   = (const float*)d_in[0];
    const int*   ei  = (const int*)d_in[1];
    const float* Wl0 = (const float*)d_in[2];
    const float* Wr0 = (const float*)d_in[4];
    const float* g0  = (const float*)d_in[5];
    const float* b0  = (const float*)d_in[6];
    const float* Wl1 = (const float*)d_in[7];
    const float* Wr1 = (const float*)d_in[9];
    const float* g1  = (const float*)d_in[10];
    const float* b1  = (const float*)d_in[11];
    const float* Wl2 = (const float*)d_in[12];
    const float* Wr2 = (const float*)d_in[14];
    const float* g2  = (const float*)d_in[15];
    const float* b2  = (const float*)d_in[16];
    float* out = (float*)d_out;

    char* ws = (char*)d_ws;
    size_t off = 0;
    auto alloc = [&](size_t bytes) -> void* {
        void* p = ws + off;
        off = (off + bytes + 255) & ~(size_t)255;
        return p;
    };
    float*          Z  = (float*)alloc((size_t)NN * 256 * 4);
    unsigned short* F0 = (unsigned short*)alloc((size_t)NN * 256 * 2);  // layer0 [mean|x]
    unsigned short* F1 = (unsigned short*)alloc((size_t)NN * 512 * 2);  // layers 1&2 [mean|h]
    int*   cnt       = (int*)alloc((size_t)NN * 4);
    int*   cursor    = (int*)alloc((size_t)NN * 4);
    int*   row_start = (int*)alloc((size_t)(NN + 1) * 4);
    int*   col       = (int*)alloc((size_t)NE * 4);
    int*   bsum      = (int*)alloc(64 * 4);
    int*   boff      = (int*)alloc(64 * 4);
    float* stats     = (float*)alloc(3 * 512 * 4);
    float* ss0       = (float*)alloc(512 * 4);
    float* ss1       = (float*)alloc(512 * 4);
    float* ss2       = (float*)alloc(512 * 4);
    unsigned short* Wb0 = (unsigned short*)alloc((size_t)256 * 256 * 2);
    unsigned short* Wb1 = (unsigned short*)alloc((size_t)256 * 512 * 2);
    unsigned short* Wb2 = (unsigned short*)alloc((size_t)256 * 512 * 2);

    hipMemsetAsync(cnt, 0, (size_t)NN * 4, stream);
    hipMemsetAsync(stats, 0, 3 * 512 * 4, stream);

    // CSR + conversions
    k_count<<<(NE + 255) / 256, 256, 0, stream>>>(ei + NE, cnt);
    k_scanA<<<NB, 1024, 0, stream>>>(cnt, row_start, bsum);
    k_scanB<<<1, 64, 0, stream>>>(bsum, boff, row_start);
    k_scanC<<<NB, 1024, 0, stream>>>(row_start, boff, cursor);
    k_scatter<<<(NE + 255) / 256, 256, 0, stream>>>(ei, ei + NE, cursor, col);
    k_f2b_x<<<(NN * 32 + 255) / 256, 256, 0, stream>>>(x, F0);
    k_packw<<<(256 * 256 + 255) / 256, 256, 0, stream>>>(Wl0, Wr0, Wb0, 128);
    k_packw<<<(256 * 512 + 255) / 256, 256, 0, stream>>>(Wl1, Wr1, Wb1, 256);
    k_packw<<<(256 * 512 + 255) / 256, 256, 0, stream>>>(Wl2, Wr2, Wb2, 256);

    int ggrid = (NN + 127) / 128;

    // ---- Layer 0 (C=128, K=256) ----
    k_agg2<128, 256><<<(NN + 15) / 16, 256, 0, stream>>>(F0, row_start, col);
    k_gemm2<256><<<ggrid, 512, 0, stream>>>(F0, Wb0, Z, stats);
    k_bnfin<<<1, 256, 0, stream>>>(stats, g0, b0, ss0);
    k_bnapply_b<<<12500, 256, 0, stream>>>(Z, ss0, F1);

    // ---- Layer 1 (C=256, K=512) ----
    k_agg2<256, 512><<<(NN + 7) / 8, 256, 0, stream>>>(F1, row_start, col);
    k_gemm2<512><<<ggrid, 512, 0, stream>>>(F1, Wb1, Z, stats + 512);
    k_bnfin<<<1, 256, 0, stream>>>(stats + 512, g1, b1, ss1);
    k_bnapply_b<<<12500, 256, 0, stream>>>(Z, ss1, F1);

    // ---- Layer 2 (C=256, K=512) ----
    k_agg2<256, 512><<<(NN + 7) / 8, 256, 0, stream>>>(F1, row_start, col);
    k_gemm2<512><<<ggrid, 512, 0, stream>>>(F1, Wb2, Z, stats + 1024);
    k_bnfin<<<1, 256, 0, stream>>>(stats + 1024, g2, b2, ss2);
    k_bnapply_f<<<12500, 256, 0, stream>>>(Z, ss2, out);
}

// Round 5
// 408.676 us; speedup vs baseline: 2.6822x; 1.0049x over previous
//
#include <hip/hip_runtime.h>
#include <hip/hip_bf16.h>

#define NN 50000
#define NE 800000
#define NB ((NN + 1023) / 1024)

typedef __attribute__((ext_vector_type(8))) short short8;
typedef __attribute__((ext_vector_type(4))) float f32x4;

#define AS1 __attribute__((address_space(1)))
#define AS3 __attribute__((address_space(3)))

__device__ inline float bf2f(unsigned short u) {
    unsigned v = (unsigned)u << 16;
    return __builtin_bit_cast(float, v);
}
__device__ inline unsigned short f2bf(float f) {
    return __builtin_bit_cast(unsigned short, __float2bfloat16(f));
}

// ---------------- prep: zero cnt/stats, x->bf16, pack weights (one launch) ----------------
__device__ inline void packw_dev(const float* __restrict__ Wl, const float* __restrict__ Wr,
                                 unsigned short* __restrict__ Wb, int C, int idx) {
    int K = 2 * C;
    if (idx >= 256 * K) return;
    int n = idx / K, k = idx % K;
    float v = (k < C) ? Wl[n * C + k] : Wr[n * C + (k - C)];
    Wb[idx] = f2bf(v);
}

__global__ __launch_bounds__(256) void k_prep(const float* __restrict__ x,
                                              const float* __restrict__ Wl0, const float* __restrict__ Wr0,
                                              const float* __restrict__ Wl1, const float* __restrict__ Wr1,
                                              const float* __restrict__ Wl2, const float* __restrict__ Wr2,
                                              unsigned short* __restrict__ F0,
                                              unsigned short* __restrict__ Wb0,
                                              unsigned short* __restrict__ Wb1,
                                              unsigned short* __restrict__ Wb2,
                                              int* __restrict__ cnt, float* __restrict__ stats) {
    int b = blockIdx.x, t = threadIdx.x;
    if (b < 6250) {  // x fp32 [NN][128] -> F0[:,128:256] bf16
        int i = b * 256 + t;
        if (i < NN * 32) {
            int row = i >> 5, c4 = (i & 31) * 4;
            float4 v = reinterpret_cast<const float4*>(x)[i];
            ushort4 o;
            o.x = f2bf(v.x); o.y = f2bf(v.y); o.z = f2bf(v.z); o.w = f2bf(v.w);
            *reinterpret_cast<ushort4*>(F0 + (size_t)row * 256 + 128 + c4) = o;
        }
        return;
    }
    b -= 6250;
    if (b < 256) { packw_dev(Wl0, Wr0, Wb0, 128, b * 256 + t); return; }
    b -= 256;
    if (b < 512) { packw_dev(Wl1, Wr1, Wb1, 256, b * 256 + t); return; }
    b -= 512;
    if (b < 512) { packw_dev(Wl2, Wr2, Wb2, 256, b * 256 + t); return; }
    b -= 512;
    if (b < 196) { int i = b * 256 + t; if (i < NN) cnt[i] = 0; return; }
    b -= 196;
    if (b < 6) { int i = b * 256 + t; if (i < 1536) stats[i] = 0.f; return; }
}
#define PREP_BLOCKS (6250 + 256 + 512 + 512 + 196 + 6)

// ---------------- CSR build ----------------
__global__ __launch_bounds__(256) void k_count(const int* __restrict__ dst, int* __restrict__ cnt) {
    int e = blockIdx.x * 256 + threadIdx.x;
    if (e < NE) atomicAdd(&cnt[dst[e]], 1);
}

__global__ __launch_bounds__(1024) void k_scanA(const int* __restrict__ cnt, int* __restrict__ row_start,
                                                int* __restrict__ bsum) {
    __shared__ int wsum[16];
    int t = threadIdx.x, lane = t & 63, wid = t >> 6;
    int i = blockIdx.x * 1024 + t;
    int v = (i < NN) ? cnt[i] : 0;
    int x = v;
    #pragma unroll
    for (int off = 1; off < 64; off <<= 1) {
        int y = __shfl_up(x, off, 64);
        if (lane >= off) x += y;
    }
    if (lane == 63) wsum[wid] = x;
    __syncthreads();
    if (t < 16) {
        int s = wsum[t];
        #pragma unroll
        for (int off = 1; off < 16; off <<= 1) {
            int y = __shfl_up(s, off, 16);
            if (t >= off) s += y;
        }
        wsum[t] = s;
    }
    __syncthreads();
    int pre = wid ? wsum[wid - 1] : 0;
    if (i < NN) row_start[i] = pre + x - v;
    if (t == 0) bsum[blockIdx.x] = wsum[15];
}

__global__ __launch_bounds__(64) void k_scanB(const int* __restrict__ bsum, int* __restrict__ boff,
                                              int* __restrict__ row_start) {
    int l = threadIdx.x;
    int v = (l < NB) ? bsum[l] : 0;
    int x = v;
    #pragma unroll
    for (int off = 1; off < 64; off <<= 1) {
        int y = __shfl_up(x, off, 64);
        if (l >= off) x += y;
    }
    boff[l] = x - v;
    if (l == 63) row_start[NN] = x;
}

__global__ __launch_bounds__(1024) void k_scanC(int* __restrict__ row_start, const int* __restrict__ boff,
                                                int* __restrict__ cursor) {
    int i = blockIdx.x * 1024 + threadIdx.x;
    if (i < NN) {
        int rs = row_start[i] + boff[blockIdx.x];
        row_start[i] = rs;
        cursor[i] = rs;
    }
}

__global__ __launch_bounds__(256) void k_scatter(const int* __restrict__ src, const int* __restrict__ dst,
                                                 int* __restrict__ cursor, int* __restrict__ col) {
    int e = blockIdx.x * 256 + threadIdx.x;
    if (e >= NE) return;
    int d = dst[e];
    int p = atomicAdd(&cursor[d], 1);
    col[p] = src[e];
}

// ---------------- mean aggregation: unroll 8, reads F[:,C:], writes F[:,:C] ----------------
template <int C, int S>
__global__ __launch_bounds__(256) void k_agg3(unsigned short* __restrict__ F,
                                              const int* __restrict__ row_start,
                                              const int* __restrict__ col) {
    constexpr int LPN = C / 8;       // lanes per node
    constexpr int NPB = 256 / LPN;   // nodes per block
    int l = threadIdx.x & (LPN - 1);
    int n = blockIdx.x * NPB + (threadIdx.x / LPN);
    if (n >= NN) return;
    int beg = row_start[n], end = row_start[n + 1];
    float inv = 1.0f / (float)((end - beg) > 1 ? (end - beg) : 1);
    float a[8] = {0.f, 0.f, 0.f, 0.f, 0.f, 0.f, 0.f, 0.f};
    const unsigned short* hp = F + C + l * 8;  // h half
    for (int base = beg; base < end; base += LPN) {
        int idx = base + l;
        int my = (idx < end) ? col[idx] : 0;
        int cnt = end - base; if (cnt > LPN) cnt = LPN;
        int j = 0;
        for (; j + 8 <= cnt; j += 8) {
            int s[8];
            #pragma unroll
            for (int q = 0; q < 8; ++q) s[q] = __shfl(my, j + q, LPN);
            short8 v[8];
            #pragma unroll
            for (int q = 0; q < 8; ++q) v[q] = *reinterpret_cast<const short8*>(hp + (size_t)s[q] * S);
            #pragma unroll
            for (int q = 0; q < 8; ++q)
                #pragma unroll
                for (int k = 0; k < 8; ++k) a[k] += bf2f((unsigned short)v[q][k]);
        }
        for (; j + 4 <= cnt; j += 4) {
            int s0 = __shfl(my, j + 0, LPN);
            int s1 = __shfl(my, j + 1, LPN);
            int s2 = __shfl(my, j + 2, LPN);
            int s3 = __shfl(my, j + 3, LPN);
            short8 v0 = *reinterpret_cast<const short8*>(hp + (size_t)s0 * S);
            short8 v1 = *reinterpret_cast<const short8*>(hp + (size_t)s1 * S);
            short8 v2 = *reinterpret_cast<const short8*>(hp + (size_t)s2 * S);
            short8 v3 = *reinterpret_cast<const short8*>(hp + (size_t)s3 * S);
            #pragma unroll
            for (int k = 0; k < 8; ++k) {
                a[k] += bf2f((unsigned short)v0[k]);
                a[k] += bf2f((unsigned short)v1[k]);
                a[k] += bf2f((unsigned short)v2[k]);
                a[k] += bf2f((unsigned short)v3[k]);
            }
        }
        for (; j < cnt; ++j) {
            int s = __shfl(my, j, LPN);
            short8 v = *reinterpret_cast<const short8*>(hp + (size_t)s * S);
            #pragma unroll
            for (int k = 0; k < 8; ++k) a[k] += bf2f((unsigned short)v[k]);
        }
    }
    unsigned short o[8];
    #pragma unroll
    for (int k = 0; k < 8; ++k) o[k] = f2bf(a[k] * inv);
    *reinterpret_cast<short8*>(F + (size_t)n * S + l * 8) = *reinterpret_cast<short8*>(o);
}

// ---------------- LDS-staged MFMA GEMM: zb = bf16(F @ Wb^T), fused BN stats ----------------
// 512 threads = 8 waves (2 row-groups x 4 col-groups). Tile 128 x 256, BK=32, double-buffered LDS.
template <int K>
__global__ __launch_bounds__(512) void k_gemm3(const unsigned short* __restrict__ F,  // [NN][K]
                                               const unsigned short* __restrict__ Wb, // [256][K]
                                               unsigned short* __restrict__ zb, int ZS, int zoff,
                                               float* __restrict__ st) {
    constexpr int T = K / 32;
    __shared__ __attribute__((aligned(16))) unsigned short sA[2][128 * 32];
    __shared__ __attribute__((aligned(16))) unsigned short sB[2][256 * 32];
    int tid = threadIdx.x;
    int lane = tid & 63, w = tid >> 6;
    int wr = w >> 2, wc = w & 3;
    int row0 = blockIdx.x * 128;
    int rl = lane & 15, kh = lane >> 4;

    int s_arow = tid >> 2, s_aslot = tid & 3;
    int s_akh = s_aslot ^ ((s_arow >> 1) & 3);
    int g_arow = row0 + s_arow; if (g_arow >= NN) g_arow = NN - 1;
    const unsigned short* aptr = F + (size_t)g_arow * K + s_akh * 8;

    int u0 = w * 128 + lane;
    int u1 = u0 + 64;
    int bcol0 = u0 >> 2, bkh0 = (u0 & 3) ^ ((bcol0 >> 1) & 3);
    int bcol1 = u1 >> 2, bkh1 = (u1 & 3) ^ ((bcol1 >> 1) & 3);
    const unsigned short* bptr0 = Wb + (size_t)bcol0 * K + bkh0 * 8;
    const unsigned short* bptr1 = Wb + (size_t)bcol1 * K + bkh1 * 8;

    int aoff[4], boff[4];
    #pragma unroll
    for (int m = 0; m < 4; ++m) {
        int r = wr * 64 + m * 16 + rl;
        aoff[m] = r * 32 + (kh ^ ((r >> 1) & 3)) * 8;
    }
    #pragma unroll
    for (int n = 0; n < 4; ++n) {
        int c = wc * 64 + n * 16 + rl;
        boff[n] = c * 32 + (kh ^ ((c >> 1) & 3)) * 8;
    }

    f32x4 acc[4][4] = {};

    auto stage = [&](int buf, int t) {
        int k0 = t * 32;
        __builtin_amdgcn_global_load_lds((const AS1 void*)(aptr + k0),
                                         (AS3 void*)((unsigned short*)sA[buf] + w * 512), 16, 0, 0);
        __builtin_amdgcn_global_load_lds((const AS1 void*)(bptr0 + k0),
                                         (AS3 void*)((unsigned short*)sB[buf] + w * 1024), 16, 0, 0);
        __builtin_amdgcn_global_load_lds((const AS1 void*)(bptr1 + k0),
                                         (AS3 void*)((unsigned short*)sB[buf] + w * 1024 + 512), 16, 0, 0);
    };

    stage(0, 0);
    __syncthreads();
    int cur = 0;
    for (int t = 0; t < T; ++t) {
        if (t + 1 < T) stage(cur ^ 1, t + 1);
        const unsigned short* A_ = sA[cur];
        const unsigned short* B_ = sB[cur];
        short8 af[4], bf_[4];
        #pragma unroll
        for (int m = 0; m < 4; ++m) af[m] = *reinterpret_cast<const short8*>(A_ + aoff[m]);
        #pragma unroll
        for (int n = 0; n < 4; ++n) bf_[n] = *reinterpret_cast<const short8*>(B_ + boff[n]);
        #pragma unroll
        for (int m = 0; m < 4; ++m)
            #pragma unroll
            for (int n = 0; n < 4; ++n)
                acc[m][n] = __builtin_amdgcn_mfma_f32_16x16x32_bf16(af[m], bf_[n], acc[m][n], 0, 0, 0);
        __syncthreads();
        cur ^= 1;
    }

    // epilogue: bf16 store + per-column BN partial sums (fp32)
    int cbase = lane & 15;
    int rbase = (lane >> 4) * 4;
    float s1[4] = {0.f, 0.f, 0.f, 0.f};
    float s2[4] = {0.f, 0.f, 0.f, 0.f};
    #pragma unroll
    for (int m = 0; m < 4; ++m) {
        #pragma unroll
        for (int j = 0; j < 4; ++j) {
            int r = row0 + wr * 64 + m * 16 + rbase + j;
            if (r < NN) {
                #pragma unroll
                for (int n = 0; n < 4; ++n) {
                    float v = acc[m][n][j];
                    zb[(size_t)r * ZS + zoff + wc * 64 + n * 16 + cbase] = f2bf(v);
                    s1[n] += v;
                    s2[n] += v * v;
                }
            }
        }
    }
    #pragma unroll
    for (int n = 0; n < 4; ++n) {
        s1[n] += __shfl_xor(s1[n], 16);
        s1[n] += __shfl_xor(s1[n], 32);
        s2[n] += __shfl_xor(s2[n], 16);
        s2[n] += __shfl_xor(s2[n], 32);
    }
    if (lane < 16) {
        #pragma unroll
        for (int n = 0; n < 4; ++n) {
            int c = wc * 64 + n * 16 + lane;
            atomicAdd(&st[c], s1[n]);
            atomicAdd(&st[256 + c], s2[n]);
        }
    }
}

// ---------------- BatchNorm ----------------
__global__ __launch_bounds__(256) void k_bnfin(const float* __restrict__ st, const float* __restrict__ g,
                                               const float* __restrict__ b, float* __restrict__ ss) {
    int c = threadIdx.x;
    float mu = st[c] * (1.0f / NN);
    float var = st[256 + c] * (1.0f / NN) - mu * mu;
    float rstd = rsqrtf(fmaxf(var, 0.f) + 1e-5f);
    float sc = g[c] * rstd;
    ss[c] = sc;
    ss[256 + c] = b[c] - mu * sc;
}

// in-place BN+ReLU on bf16 z stored at F[:,256:512]
__global__ __launch_bounds__(256) void k_bnip(unsigned short* __restrict__ F1,
                                              const float* __restrict__ ss) {
    int i = blockIdx.x * 256 + threadIdx.x;  // NN*64 ushort4 units
    if (i >= NN * 64) return;
    int row = i >> 6, c4 = (i & 63) * 4;
    unsigned short* p = F1 + (size_t)row * 512 + 256 + c4;
    ushort4 v = *reinterpret_cast<const ushort4*>(p);
    float4 sc = *reinterpret_cast<const float4*>(&ss[c4]);
    float4 sh = *reinterpret_cast<const float4*>(&ss[256 + c4]);
    ushort4 o;
    o.x = f2bf(fmaxf(bf2f(v.x) * sc.x + sh.x, 0.f));
    o.y = f2bf(fmaxf(bf2f(v.y) * sc.y + sh.y, 0.f));
    o.z = f2bf(fmaxf(bf2f(v.z) * sc.z + sh.z, 0.f));
    o.w = f2bf(fmaxf(bf2f(v.w) * sc.w + sh.w, 0.f));
    *reinterpret_cast<ushort4*>(p) = o;
}

// final BN (no ReLU): bf16 z -> fp32 out
__global__ __launch_bounds__(256) void k_bnf(const unsigned short* __restrict__ Zb,
                                             const float* __restrict__ ss,
                                             float* __restrict__ out) {
    int i = blockIdx.x * 256 + threadIdx.x;
    if (i >= NN * 64) return;
    int c4 = (i & 63) * 4;
    ushort4 v = reinterpret_cast<const ushort4*>(Zb)[i];
    float4 sc = *reinterpret_cast<const float4*>(&ss[c4]);
    float4 sh = *reinterpret_cast<const float4*>(&ss[256 + c4]);
    float4 o;
    o.x = bf2f(v.x) * sc.x + sh.x;
    o.y = bf2f(v.y) * sc.y + sh.y;
    o.z = bf2f(v.z) * sc.z + sh.z;
    o.w = bf2f(v.w) * sc.w + sh.w;
    reinterpret_cast<float4*>(out)[i] = o;
}

extern "C" void kernel_launch(void* const* d_in, const int* in_sizes, int n_in,
                              void* d_out, int out_size, void* d_ws, size_t ws_size,
                              hipStream_t stream) {
    const float* x   = (const float*)d_in[0];
    const int*   ei  = (const int*)d_in[1];
    const float* Wl0 = (const float*)d_in[2];
    const float* Wr0 = (const float*)d_in[4];
    const float* g0  = (const float*)d_in[5];
    const float* b0  = (const float*)d_in[6];
    const float* Wl1 = (const float*)d_in[7];
    const float* Wr1 = (const float*)d_in[9];
    const float* g1  = (const float*)d_in[10];
    const float* b1  = (const float*)d_in[11];
    const float* Wl2 = (const float*)d_in[12];
    const float* Wr2 = (const float*)d_in[14];
    const float* g2  = (const float*)d_in[15];
    const float* b2  = (const float*)d_in[16];
    float* out = (float*)d_out;

    char* ws = (char*)d_ws;
    size_t off = 0;
    auto alloc = [&](size_t bytes) -> void* {
        void* p = ws + off;
        off = (off + bytes + 255) & ~(size_t)255;
        return p;
    };
    unsigned short* F0 = (unsigned short*)alloc((size_t)NN * 256 * 2);  // layer0 [mean0|x]
    unsigned short* F1 = (unsigned short*)alloc((size_t)NN * 512 * 2);  // layers 1&2 [mean|h/z]
    unsigned short* Zb = (unsigned short*)alloc((size_t)NN * 256 * 2);  // layer2 z bf16
    int*   cnt       = (int*)alloc((size_t)NN * 4);
    int*   cursor    = (int*)alloc((size_t)NN * 4);
    int*   row_start = (int*)alloc((size_t)(NN + 1) * 4);
    int*   col       = (int*)alloc((size_t)NE * 4);
    int*   bsum      = (int*)alloc(64 * 4);
    int*   boff      = (int*)alloc(64 * 4);
    float* stats     = (float*)alloc(3 * 512 * 4);
    float* ss0       = (float*)alloc(512 * 4);
    float* ss1       = (float*)alloc(512 * 4);
    float* ss2       = (float*)alloc(512 * 4);
    unsigned short* Wb0 = (unsigned short*)alloc((size_t)256 * 256 * 2);
    unsigned short* Wb1 = (unsigned short*)alloc((size_t)256 * 512 * 2);
    unsigned short* Wb2 = (unsigned short*)alloc((size_t)256 * 512 * 2);

    // prep (zero cnt/stats, convert x, pack weights) + CSR build
    k_prep<<<PREP_BLOCKS, 256, 0, stream>>>(x, Wl0, Wr0, Wl1, Wr1, Wl2, Wr2,
                                            F0, Wb0, Wb1, Wb2, cnt, stats);
    k_count<<<(NE + 255) / 256, 256, 0, stream>>>(ei + NE, cnt);
    k_scanA<<<NB, 1024, 0, stream>>>(cnt, row_start, bsum);
    k_scanB<<<1, 64, 0, stream>>>(bsum, boff, row_start);
    k_scanC<<<NB, 1024, 0, stream>>>(row_start, boff, cursor);
    k_scatter<<<(NE + 255) / 256, 256, 0, stream>>>(ei, ei + NE, cursor, col);

    int ggrid = (NN + 127) / 128;

    // ---- Layer 0 (C=128, K=256): z0 -> F1[:,256:] ----
    k_agg3<128, 256><<<(NN + 15) / 16, 256, 0, stream>>>(F0, row_start, col);
    k_gemm3<256><<<ggrid, 512, 0, stream>>>(F0, Wb0, F1, 512, 256, stats);
    k_bnfin<<<1, 256, 0, stream>>>(stats, g0, b0, ss0);
    k_bnip<<<12500, 256, 0, stream>>>(F1, ss0);

    // ---- Layer 1 (C=256, K=512): z1 -> F1[:,256:] (rows block-private, race-free) ----
    k_agg3<256, 512><<<(NN + 7) / 8, 256, 0, stream>>>(F1, row_start, col);
    k_gemm3<512><<<ggrid, 512, 0, stream>>>(F1, Wb1, F1, 512, 256, stats + 512);
    k_bnfin<<<1, 256, 0, stream>>>(stats + 512, g1, b1, ss1);
    k_bnip<<<12500, 256, 0, stream>>>(F1, ss1);

    // ---- Layer 2 (C=256, K=512): z2 -> Zb, final BN -> fp32 out ----
    k_agg3<256, 512><<<(NN + 7) / 8, 256, 0, stream>>>(F1, row_start, col);
    k_gemm3<512><<<ggrid, 512, 0, stream>>>(F1, Wb2, Zb, 256, 0, stats + 1024);
    k_bnfin<<<1, 256, 0, stream>>>(stats + 1024, g2, b2, ss2);
    k_bnf<<<12500, 256, 0, stream>>>(Zb, ss2, out);
}